// Round 3
// baseline (285.847 us; speedup 1.0000x reference)
//
#include <hip/hip_runtime.h>
#include <hip/hip_bf16.h>
#include <stdint.h>

// Problem constants: B=2, S=T=2048, D=2048, N=8 heads, K=1 kv head, H=256
#define BB 2
#define SS 2048
#define DD 2048
#define NHEAD 8
#define HH 256

typedef __bf16 bf16_t;
typedef __bf16 bf16x8 __attribute__((ext_vector_type(8)));
typedef __bf16 bf16x4v __attribute__((ext_vector_type(4)));
typedef float f32x4 __attribute__((ext_vector_type(4)));

__device__ static inline void gload_lds16(const void* g, void* l) {
  __builtin_amdgcn_global_load_lds(
      (__attribute__((address_space(1))) void*)(g),
      (__attribute__((address_space(3))) void*)(l), 16, 0, 0);
}

// ---------------- x -> bf16 ----------------
__global__ void cvt_x_kernel(const float* __restrict__ x, bf16_t* __restrict__ xb) {
  size_t i = ((size_t)blockIdx.x * 256 + threadIdx.x) * 4;
  float4 v = *(const float4*)(x + i);
  bf16x4v o = {(bf16_t)v.x, (bf16_t)v.y, (bf16_t)v.z, (bf16_t)v.w};
  *(bf16x4v*)(xb + i) = o;
}

// ---------------- tiled transpose+convert: out[c][r] = (bf16)in[r][c] ----------------
__global__ void transpose_cvt(const float* __restrict__ in, bf16_t* __restrict__ out,
                              int R, int C) {
  __shared__ float tile[32][33];
  int bx = blockIdx.x, by = blockIdx.y, z = blockIdx.z;
  in  += (size_t)z * R * C;
  out += (size_t)z * R * C;
  int tx = threadIdx.x & 31, ty = threadIdx.x >> 5;  // 32x8
#pragma unroll
  for (int k = 0; k < 4; ++k) {
    int r = by * 32 + ty + k * 8, c = bx * 32 + tx;
    tile[ty + k * 8][tx] = in[(size_t)r * C + c];
  }
  __syncthreads();
#pragma unroll
  for (int k = 0; k < 4; ++k) {
    int c = bx * 32 + ty + k * 8, r = by * 32 + tx;
    out[(size_t)c * R + r] = (bf16_t)tile[tx][ty + k * 8];
  }
}

// ---------------- GEMM: C[M][Nc] = A[M][Kd] * BT[Nc][Kd]^T  (bf16 in, fp32 acc) ----------------
template <int OUT_F32>
__global__ __launch_bounds__(256) void gemm_bt(const bf16_t* __restrict__ A,
                                               const bf16_t* __restrict__ BT,
                                               void* __restrict__ C,
                                               int M, int Nc, int Kd) {
  __shared__ bf16_t At[128 * 64];
  __shared__ bf16_t Bt[128 * 64];
  const int ntiles = Nc >> 7;
  int bid = blockIdx.x;
  int mt = bid / ntiles, ntb = bid % ntiles;
  int t = threadIdx.x;
  int lane = t & 63, w = t >> 6;
  int wm = w >> 1, wn = w & 1;
  int l15 = lane & 15, lg = lane >> 4;
  f32x4 acc[4][4] = {};
  for (int kt = 0; kt < Kd; kt += 64) {
#pragma unroll
    for (int r = 0; r < 4; ++r) {
      int o = t * 16 + r * 4096;     // byte offset into 16KB tile
      int row = o >> 7;              // 128B per row (64 bf16)
      int cb = o & 127;
      gload_lds16(A + (size_t)(mt * 128 + row) * Kd + kt + (cb >> 1), (char*)At + o);
      gload_lds16(BT + (size_t)(ntb * 128 + row) * Kd + kt + (cb >> 1), (char*)Bt + o);
    }
    __syncthreads();
#pragma unroll
    for (int ks = 0; ks < 2; ++ks) {
      bf16x8 af[4], bfr[4];
#pragma unroll
      for (int i = 0; i < 4; ++i) {
        af[i]  = *(const bf16x8*)(At + (wm * 64 + i * 16 + l15) * 64 + ks * 32 + lg * 8);
        bfr[i] = *(const bf16x8*)(Bt + (wn * 64 + i * 16 + l15) * 64 + ks * 32 + lg * 8);
      }
      __builtin_amdgcn_s_setprio(1);
#pragma unroll
      for (int i = 0; i < 4; ++i)
#pragma unroll
        for (int j = 0; j < 4; ++j)
          acc[i][j] = __builtin_amdgcn_mfma_f32_16x16x32_bf16(af[i], bfr[j], acc[i][j], 0, 0, 0);
      __builtin_amdgcn_s_setprio(0);
    }
    __syncthreads();
  }
#pragma unroll
  for (int i = 0; i < 4; ++i)
#pragma unroll
    for (int j = 0; j < 4; ++j) {
      int row = mt * 128 + wm * 64 + i * 16 + lg * 4;
      int col = ntb * 128 + wn * 64 + j * 16 + l15;
#pragma unroll
      for (int v = 0; v < 4; ++v) {
        if (OUT_F32)
          ((float*)C)[(size_t)(row + v) * Nc + col] = acc[i][j][v];
        else
          ((bf16_t*)C)[(size_t)(row + v) * Nc + col] = (bf16_t)acc[i][j][v];
      }
    }
}

// ---------------- RoPE (in-place) on fused qkv [4096][2560] ----------------
__global__ void rope_kernel(bf16_t* __restrict__ qkv, const int* __restrict__ positions) {
  int idx = blockIdx.x * 256 + threadIdx.x;
  const int QP = 4096 * 8 * 128;
  int i, row;
  bf16_t *p1, *p2;
  float scl;
  if (idx < QP) {
    i = idx & 127;
    int nh = (idx >> 7) & 7;
    row = idx >> 10;
    p1 = qkv + (size_t)row * 2560 + nh * 256 + i;
    p2 = p1 + 128;
    scl = 0.0625f;  // H^-0.5 = 1/16
  } else {
    int kk = idx - QP;
    if (kk >= 4096 * 128) return;
    i = kk & 127;
    row = kk >> 7;
    p1 = qkv + (size_t)row * 2560 + 2048 + i;
    p2 = p1 + 128;
    scl = 1.0f;
  }
  float pos = (float)positions[row];
  float ang = pos * __expf(-(float)i * (9.2103403719761836f / 128.f));
  float s = sinf(ang), c = cosf(ang);
  float x1 = (float)*p1, x2 = (float)*p2;
  *p1 = (bf16_t)((x1 * c - x2 * s) * scl);
  *p2 = (bf16_t)((x2 * c + x1 * s) * scl);
}

// ---------------- V transpose (LDS-tiled): vt[b][h][s] = qkv[(b*S+s)][2304+h] ----------------
__global__ void vt_kernel(const bf16_t* __restrict__ qkv, bf16_t* __restrict__ vt) {
  __shared__ bf16_t tile[32][34];
  int bx = blockIdx.x;  // s-tile (64)
  int by = blockIdx.y;  // h-tile (8)
  int b = blockIdx.z;
  int tx = threadIdx.x & 31, ty = threadIdx.x >> 5;
#pragma unroll
  for (int k = 0; k < 4; ++k) {
    int s = bx * 32 + ty + k * 8, h = by * 32 + tx;
    tile[ty + k * 8][tx] = qkv[((size_t)(b * SS + s)) * 2560 + 2304 + h];
  }
  __syncthreads();
#pragma unroll
  for (int k = 0; k < 4; ++k) {
    int h = by * 32 + ty + k * 8, s = bx * 32 + tx;
    vt[((size_t)(b * HH + h)) * 2048 + s] = tile[tx][ty + k * 8];
  }
}

// ---------------- Flash attention ----------------
// grid 256, block 512 (8 waves x 16 q-rows = 128-row q-tile). Each block does
// q-tiles (pr) and (15-pr): 2*qt+2 kv-iters each -> 34 iters/block, balanced.
// K/V double-buffered in LDS; next tile's global_load_lds issued BEFORE compute
// of current tile, single barrier per iter (implicit vmcnt(0) drains after the
// latency has been hidden under compute). Defer-max softmax (THR=8).
__global__ __launch_bounds__(512) void flash_kernel(const bf16_t* __restrict__ qkv,
                                                    const bf16_t* __restrict__ vtg,
                                                    bf16_t* __restrict__ enc) {
  __shared__ bf16_t Kt[2][64 * 256];   // [s][h], 512B rows, XOR-swizzled
  __shared__ bf16_t Vt[2][256 * 64];   // [h][s], 128B rows, XOR-swizzled
  __shared__ bf16_t Pl[8][16 * 64];    // per-wave P, 128B rows, XOR-swizzled
  int bid = blockIdx.x;
  int b = bid >> 7, n = (bid >> 4) & 7, pr = bid & 15;
  int t = threadIdx.x, lane = t & 63, w = t >> 6;
  int l15 = lane & 15, lg = lane >> 4;
  bf16_t* P = Pl[w];
  for (int half = 0; half < 2; ++half) {
    int qtile = half ? (15 - pr) : pr;
    int ktlast = 2 * qtile + 1;          // last kv tile index for this q-tile
    int ktd = 2 * qtile + (w >> 2);      // this wave's diagonal kv tile
    // Q fragments (16 rows x 256 h) in registers
    bf16x8 qf[8];
    const bf16_t* qrow =
        qkv + ((size_t)(b * SS + qtile * 128 + w * 16 + l15)) * 2560 + n * 256;
#pragma unroll
    for (int kk = 0; kk < 8; ++kk) qf[kk] = *(const bf16x8*)(qrow + kk * 32 + lg * 8);
    f32x4 accO[16];
#pragma unroll
    for (int ht = 0; ht < 16; ++ht) accO[ht] = f32x4{0.f, 0.f, 0.f, 0.f};
    float m_r[4], l_r[4];
#pragma unroll
    for (int v = 0; v < 4; ++v) { m_r[v] = -1e30f; l_r[v] = 0.f; }
    int cur = 0;
    // prologue: stage tile 0 into buf 0
#pragma unroll
    for (int r = 0; r < 4; ++r) {
      int o = t * 16 + r * 8192;
      {  // K [64][256]: 512B rows
        int row = o >> 9, cb = (o & 511) ^ ((row & 7) << 4);
        gload_lds16(qkv + ((size_t)(b * SS + row)) * 2560 + 2048 + (cb >> 1),
                    (char*)Kt[0] + o);
      }
      {  // V^T [256][64]: 128B rows
        int row = o >> 7, cb = (o & 127) ^ ((row & 7) << 4);
        gload_lds16(vtg + ((size_t)(b * HH + row)) * 2048 + (cb >> 1), (char*)Vt[0] + o);
      }
    }
    __syncthreads();
    for (int kt = 0; kt <= ktlast; ++kt) {
      // issue next tile's staging loads FIRST (hidden under compute below)
      if (kt < ktlast) {
        int nxt = cur ^ 1, ktn = kt + 1;
#pragma unroll
        for (int r = 0; r < 4; ++r) {
          int o = t * 16 + r * 8192;
          {
            int row = o >> 9, cb = (o & 511) ^ ((row & 7) << 4);
            gload_lds16(qkv + ((size_t)(b * SS + ktn * 64 + row)) * 2560 + 2048 + (cb >> 1),
                        (char*)Kt[nxt] + o);
          }
          {
            int row = o >> 7, cb = (o & 127) ^ ((row & 7) << 4);
            gload_lds16(vtg + ((size_t)(b * HH + row)) * 2048 + ktn * 64 + (cb >> 1),
                        (char*)Vt[nxt] + o);
          }
        }
      }
      if (kt <= ktd) {  // active wave (kt beyond diagonal is fully masked)
        const bf16_t* Kc = Kt[cur];
        const bf16_t* Vc = Vt[cur];
        // QK^T: 16 q-rows x 64 s
        f32x4 sc4[4];
#pragma unroll
        for (int ntt = 0; ntt < 4; ++ntt) sc4[ntt] = f32x4{0.f, 0.f, 0.f, 0.f};
        __builtin_amdgcn_s_setprio(1);
#pragma unroll
        for (int kk = 0; kk < 8; ++kk) {
          int byte0 = (kk * 32 + lg * 8) * 2;
#pragma unroll
          for (int ntt = 0; ntt < 4; ++ntt) {
            int srow = ntt * 16 + l15;
            bf16x8 kf =
                *(const bf16x8*)((const char*)Kc + srow * 512 + (byte0 ^ ((srow & 7) << 4)));
            sc4[ntt] = __builtin_amdgcn_mfma_f32_16x16x32_bf16(qf[kk], kf, sc4[ntt], 0, 0, 0);
          }
        }
        __builtin_amdgcn_s_setprio(0);
        if (kt == ktd) {  // causal mask on this wave's diagonal tile
#pragma unroll
          for (int ntt = 0; ntt < 4; ++ntt) {
            int s_g = kt * 64 + ntt * 16 + l15;
#pragma unroll
            for (int v = 0; v < 4; ++v) {
              int r_g = qtile * 128 + w * 16 + lg * 4 + v;
              if (s_g > r_g) sc4[ntt][v] = -1e30f;
            }
          }
        }
        // online softmax with defer-max (THR=8)
#pragma unroll
        for (int v = 0; v < 4; ++v) {
          float pm = fmaxf(fmaxf(sc4[0][v], sc4[1][v]), fmaxf(sc4[2][v], sc4[3][v]));
          pm = fmaxf(pm, __shfl_xor(pm, 1));
          pm = fmaxf(pm, __shfl_xor(pm, 2));
          pm = fmaxf(pm, __shfl_xor(pm, 4));
          pm = fmaxf(pm, __shfl_xor(pm, 8));
          if (pm > m_r[v] + 8.f) {  // rescale only on significant max growth
            float scale = __expf(m_r[v] - pm);
            l_r[v] *= scale;
#pragma unroll
            for (int ht = 0; ht < 16; ++ht) accO[ht][v] *= scale;
            m_r[v] = pm;
          }
          float rs = 0.f;
#pragma unroll
          for (int ntt = 0; ntt < 4; ++ntt) {
            float p = __expf(sc4[ntt][v] - m_r[v]);
            sc4[ntt][v] = p;
            rs += p;
          }
          rs += __shfl_xor(rs, 1);
          rs += __shfl_xor(rs, 2);
          rs += __shfl_xor(rs, 4);
          rs += __shfl_xor(rs, 8);
          l_r[v] += rs;
        }
        // P -> LDS (bf16, swizzled), per-wave private
#pragma unroll
        for (int ntt = 0; ntt < 4; ++ntt)
#pragma unroll
          for (int v = 0; v < 4; ++v) {
            int row = lg * 4 + v, col = ntt * 16 + l15;
            *(bf16_t*)((char*)P + row * 128 + ((col * 2) ^ ((row & 7) << 4))) =
                (bf16_t)sc4[ntt][v];
          }
        // PV: O += P[16x64] * V[64x256]
        __builtin_amdgcn_s_setprio(1);
#pragma unroll
        for (int ks = 0; ks < 2; ++ks) {
          int pb = (ks * 32 + lg * 8) * 2;
          bf16x8 pf = *(const bf16x8*)((const char*)P + l15 * 128 + (pb ^ ((l15 & 7) << 4)));
#pragma unroll
          for (int ht = 0; ht < 16; ++ht) {
            int vrow = ht * 16 + l15;
            bf16x8 vf =
                *(const bf16x8*)((const char*)Vc + vrow * 128 + (pb ^ ((vrow & 7) << 4)));
            accO[ht] = __builtin_amdgcn_mfma_f32_16x16x32_bf16(pf, vf, accO[ht], 0, 0, 0);
          }
        }
        __builtin_amdgcn_s_setprio(0);
      }
      __syncthreads();  // implicit vmcnt(0): next tile staged; buf[cur] free to overwrite
      cur ^= 1;
    }
    // epilogue: normalize and store enc
#pragma unroll
    for (int ht = 0; ht < 16; ++ht) {
#pragma unroll
      for (int v = 0; v < 4; ++v) {
        float o = accO[ht][v] / l_r[v];
        enc[((size_t)(b * SS + qtile * 128 + w * 16 + lg * 4 + v)) * 2048 + n * 256 +
            ht * 16 + l15] = (bf16_t)o;
      }
    }
  }
}

extern "C" void kernel_launch(void* const* d_in, const int* in_sizes, int n_in,
                              void* d_out, int out_size, void* d_ws, size_t ws_size,
                              hipStream_t stream) {
  const float* x = (const float*)d_in[0];
  const int* positions = (const int*)d_in[1];
  // d_in[2] = attn_mask (causal tril) — implemented analytically
  const float* qw = (const float*)d_in[3];
  const float* kvw = (const float*)d_in[4];
  const float* outw = (const float*)d_in[5];

  char* ws = (char*)d_ws;
  if (ws_size < (size_t)75497472) return;  // need ~72MB scratch
  bf16_t* xb      = (bf16_t*)(ws);             // [4096][2048]
  bf16_t* qkvwbt  = (bf16_t*)(ws + 16777216);  // [2560][2048]: q rows 0..2047, k 2048..2303, v 2304..2559
  bf16_t* outwbt  = (bf16_t*)(ws + 27262976);  // [2048][2048]
  bf16_t* qkvb    = (bf16_t*)(ws + 35651584);  // [4096][2560]
  bf16_t* vtg     = (bf16_t*)(ws + 56623104);  // [2][256][2048]
  bf16_t* encb    = (bf16_t*)(ws + 58720256);  // [4096][2048]

  cvt_x_kernel<<<8192, 256, 0, stream>>>(x, xb);
  transpose_cvt<<<dim3(8, 64, 8), 256, 0, stream>>>(qw, qkvwbt, 2048, 256);
  transpose_cvt<<<dim3(8, 64, 2), 256, 0, stream>>>(kvw, qkvwbt + (size_t)2048 * 2048, 2048, 256);
  transpose_cvt<<<dim3(64, 64, 1), 256, 0, stream>>>(outw, outwbt, 2048, 2048);
  gemm_bt<0><<<640, 256, 0, stream>>>(xb, qkvwbt, qkvb, 4096, 2560, 2048);
  rope_kernel<<<18432, 256, 0, stream>>>(qkvb, positions);
  vt_kernel<<<dim3(64, 8, 2), 256, 0, stream>>>(qkvb, vtg);
  flash_kernel<<<256, 512, 0, stream>>>(qkvb, vtg, encb);
  gemm_bt<1><<<512, 256, 0, stream>>>(encb, outwbt, d_out, 4096, 2048, 2048);
}

// Round 4
// 268.041 us; speedup vs baseline: 1.0664x; 1.0664x over previous
//
#include <hip/hip_runtime.h>
#include <hip/hip_bf16.h>
#include <stdint.h>

// Problem constants: B=2, S=T=2048, D=2048, N=8 heads, K=1 kv head, H=256
#define BB 2
#define SS 2048
#define DD 2048
#define NHEAD 8
#define HH 256

typedef __bf16 bf16_t;
typedef __bf16 bf16x8 __attribute__((ext_vector_type(8)));
typedef __bf16 bf16x4v __attribute__((ext_vector_type(4)));
typedef float f32x4 __attribute__((ext_vector_type(4)));

__device__ static inline void gload_lds16(const void* g, void* l) {
  __builtin_amdgcn_global_load_lds(
      (__attribute__((address_space(1))) void*)(g),
      (__attribute__((address_space(3))) void*)(l), 16, 0, 0);
}

// ---------------- x -> bf16 ----------------
__global__ void cvt_x_kernel(const float* __restrict__ x, bf16_t* __restrict__ xb) {
  size_t i = ((size_t)blockIdx.x * 256 + threadIdx.x) * 4;
  float4 v = *(const float4*)(x + i);
  bf16x4v o = {(bf16_t)v.x, (bf16_t)v.y, (bf16_t)v.z, (bf16_t)v.w};
  *(bf16x4v*)(xb + i) = o;
}

// ---------------- tiled transpose+convert: out[c][r] = (bf16)in[r][c] ----------------
__global__ void transpose_cvt(const float* __restrict__ in, bf16_t* __restrict__ out,
                              int R, int C) {
  __shared__ float tile[32][33];
  int bx = blockIdx.x, by = blockIdx.y, z = blockIdx.z;
  in  += (size_t)z * R * C;
  out += (size_t)z * R * C;
  int tx = threadIdx.x & 31, ty = threadIdx.x >> 5;  // 32x8
#pragma unroll
  for (int k = 0; k < 4; ++k) {
    int r = by * 32 + ty + k * 8, c = bx * 32 + tx;
    tile[ty + k * 8][tx] = in[(size_t)r * C + c];
  }
  __syncthreads();
#pragma unroll
  for (int k = 0; k < 4; ++k) {
    int c = bx * 32 + ty + k * 8, r = by * 32 + tx;
    out[(size_t)c * R + r] = (bf16_t)tile[tx][ty + k * 8];
  }
}

// ---------------- GEMM: C[M][Nc] = A[M][Kd] * BT[Nc][Kd]^T  (bf16 in, fp32 acc) ----------------
template <int OUT_F32>
__global__ __launch_bounds__(256) void gemm_bt(const bf16_t* __restrict__ A,
                                               const bf16_t* __restrict__ BT,
                                               void* __restrict__ C,
                                               int M, int Nc, int Kd) {
  __shared__ bf16_t At[128 * 64];
  __shared__ bf16_t Bt[128 * 64];
  const int ntiles = Nc >> 7;
  int bid = blockIdx.x;
  int mt = bid / ntiles, ntb = bid % ntiles;
  int t = threadIdx.x;
  int lane = t & 63, w = t >> 6;
  int wm = w >> 1, wn = w & 1;
  int l15 = lane & 15, lg = lane >> 4;
  f32x4 acc[4][4] = {};
  for (int kt = 0; kt < Kd; kt += 64) {
#pragma unroll
    for (int r = 0; r < 4; ++r) {
      int o = t * 16 + r * 4096;     // byte offset into 16KB tile
      int row = o >> 7;              // 128B per row (64 bf16)
      int cb = o & 127;
      gload_lds16(A + (size_t)(mt * 128 + row) * Kd + kt + (cb >> 1), (char*)At + o);
      gload_lds16(BT + (size_t)(ntb * 128 + row) * Kd + kt + (cb >> 1), (char*)Bt + o);
    }
    __syncthreads();
#pragma unroll
    for (int ks = 0; ks < 2; ++ks) {
      bf16x8 af[4], bfr[4];
#pragma unroll
      for (int i = 0; i < 4; ++i) {
        af[i]  = *(const bf16x8*)(At + (wm * 64 + i * 16 + l15) * 64 + ks * 32 + lg * 8);
        bfr[i] = *(const bf16x8*)(Bt + (wn * 64 + i * 16 + l15) * 64 + ks * 32 + lg * 8);
      }
      __builtin_amdgcn_s_setprio(1);
#pragma unroll
      for (int i = 0; i < 4; ++i)
#pragma unroll
        for (int j = 0; j < 4; ++j)
          acc[i][j] = __builtin_amdgcn_mfma_f32_16x16x32_bf16(af[i], bfr[j], acc[i][j], 0, 0, 0);
      __builtin_amdgcn_s_setprio(0);
    }
    __syncthreads();
  }
#pragma unroll
  for (int i = 0; i < 4; ++i)
#pragma unroll
    for (int j = 0; j < 4; ++j) {
      int row = mt * 128 + wm * 64 + i * 16 + lg * 4;
      int col = ntb * 128 + wn * 64 + j * 16 + l15;
#pragma unroll
      for (int v = 0; v < 4; ++v) {
        if (OUT_F32)
          ((float*)C)[(size_t)(row + v) * Nc + col] = acc[i][j][v];
        else
          ((bf16_t*)C)[(size_t)(row + v) * Nc + col] = (bf16_t)acc[i][j][v];
      }
    }
}

// ---------------- RoPE (in-place) on fused qkv [4096][2560] ----------------
__global__ void rope_kernel(bf16_t* __restrict__ qkv, const int* __restrict__ positions) {
  int idx = blockIdx.x * 256 + threadIdx.x;
  const int QP = 4096 * 8 * 128;
  int i, row;
  bf16_t *p1, *p2;
  float scl;
  if (idx < QP) {
    i = idx & 127;
    int nh = (idx >> 7) & 7;
    row = idx >> 10;
    p1 = qkv + (size_t)row * 2560 + nh * 256 + i;
    p2 = p1 + 128;
    scl = 0.0625f;  // H^-0.5 = 1/16
  } else {
    int kk = idx - QP;
    if (kk >= 4096 * 128) return;
    i = kk & 127;
    row = kk >> 7;
    p1 = qkv + (size_t)row * 2560 + 2048 + i;
    p2 = p1 + 128;
    scl = 1.0f;
  }
  float pos = (float)positions[row];
  float ang = pos * __expf(-(float)i * (9.2103403719761836f / 128.f));
  float s = sinf(ang), c = cosf(ang);
  float x1 = (float)*p1, x2 = (float)*p2;
  *p1 = (bf16_t)((x1 * c - x2 * s) * scl);
  *p2 = (bf16_t)((x2 * c + x1 * s) * scl);
}

// ---------------- V transpose (LDS-tiled): vt[b][h][s] = qkv[(b*S+s)][2304+h] ----------------
__global__ void vt_kernel(const bf16_t* __restrict__ qkv, bf16_t* __restrict__ vt) {
  __shared__ bf16_t tile[32][34];
  int bx = blockIdx.x;  // s-tile (64)
  int by = blockIdx.y;  // h-tile (8)
  int b = blockIdx.z;
  int tx = threadIdx.x & 31, ty = threadIdx.x >> 5;
#pragma unroll
  for (int k = 0; k < 4; ++k) {
    int s = bx * 32 + ty + k * 8, h = by * 32 + tx;
    tile[ty + k * 8][tx] = qkv[((size_t)(b * SS + s)) * 2560 + 2304 + h];
  }
  __syncthreads();
#pragma unroll
  for (int k = 0; k < 4; ++k) {
    int h = by * 32 + ty + k * 8, s = bx * 32 + tx;
    vt[((size_t)(b * HH + h)) * 2048 + s] = tile[tx][ty + k * 8];
  }
}

// ---------------- Flash attention (fat waves, swapped QK^T) ----------------
// grid 256, block 256 (4 waves x 32 q-rows = 128-row q-tile, M_rep=2).
// Each kf/vf LDS read feeds 2 MFMAs -> LDS read traffic per FLOP halved.
// QK computed as mfma(K, Q) -> S^T: q on lane axis (col=l15), s per-lane
// (16 values) -> softmax reduction is in-lane + 2 shfls; stats are scalars;
// P written as 4x ds_write_b64. Defer-max (THR=8) rescale via __any.
// K/V double-buffered (144KB LDS, 1 block/CU); next tile staged issue-early.
__global__ __launch_bounds__(256, 1) void flash_kernel(const bf16_t* __restrict__ qkv,
                                                       const bf16_t* __restrict__ vtg,
                                                       bf16_t* __restrict__ enc) {
  __shared__ bf16_t Kt[2][64 * 256];   // [s][h], 512B rows, XOR-swizzled
  __shared__ bf16_t Vt[2][256 * 64];   // [h][s], 128B rows, XOR-swizzled
  __shared__ bf16_t Pl[4][2][16 * 64]; // per-wave, per-mtile P[q][s], swizzled
  int bid = blockIdx.x;
  int b = bid >> 7, n = (bid >> 4) & 7, qtile = bid & 15;
  int t = threadIdx.x, lane = t & 63, w = t >> 6;
  int l15 = lane & 15, lg = lane >> 4;
  int ktlast = 2 * qtile + 1;
  int ktd = 2 * qtile + (w >> 1);  // this wave's diagonal kv tile
  // Q fragments: rows qtile*128 + w*32 + m*16 + l15
  bf16x8 qf[2][8];
#pragma unroll
  for (int m = 0; m < 2; ++m) {
    const bf16_t* qrow =
        qkv + ((size_t)(b * SS + qtile * 128 + w * 32 + m * 16 + l15)) * 2560 + n * 256;
#pragma unroll
    for (int kk = 0; kk < 8; ++kk) qf[m][kk] = *(const bf16x8*)(qrow + kk * 32 + lg * 8);
  }
  f32x4 accO[2][16];
#pragma unroll
  for (int m = 0; m < 2; ++m)
#pragma unroll
    for (int ht = 0; ht < 16; ++ht) accO[m][ht] = f32x4{0.f, 0.f, 0.f, 0.f};
  float m_r[2] = {-1e30f, -1e30f}, l_r[2] = {0.f, 0.f};
  // staging source pointers (pre-swizzled global addresses, LDS dest linear)
  int row0k = t >> 5;
  int cbk = ((t * 16) & 511) ^ ((row0k & 7) << 4);
  const bf16_t* kptr = qkv + ((size_t)(b * SS + row0k)) * 2560 + 2048 + (cbk >> 1);
  int row0v = t >> 3;
  int cbv = ((t & 7) * 16) ^ ((row0v & 7) << 4);
  const bf16_t* vptr = vtg + ((size_t)(b * HH + row0v)) * 2048 + (cbv >> 1);
  // prologue: stage tile 0 into buf 0
#pragma unroll
  for (int r = 0; r < 8; ++r) {
    gload_lds16(kptr + (size_t)r * 8 * 2560, (char*)Kt[0] + t * 16 + r * 4096);
    gload_lds16(vptr + (size_t)r * 32 * 2048, (char*)Vt[0] + t * 16 + r * 4096);
  }
  __syncthreads();
  int cur = 0;
  for (int kt = 0; kt <= ktlast; ++kt) {
    // issue next tile's staging FIRST (hidden under compute below)
    if (kt < ktlast) {
      int nxt = cur ^ 1;
      const bf16_t* ks = kptr + (size_t)(kt + 1) * 64 * 2560;
      const bf16_t* vs = vptr + (size_t)(kt + 1) * 64;
#pragma unroll
      for (int r = 0; r < 8; ++r) {
        gload_lds16(ks + (size_t)r * 8 * 2560, (char*)Kt[nxt] + t * 16 + r * 4096);
        gload_lds16(vs + (size_t)r * 32 * 2048, (char*)Vt[nxt] + t * 16 + r * 4096);
      }
    }
    if (kt <= ktd) {
      const char* Kc = (const char*)Kt[cur];
      const char* Vc = (const char*)Vt[cur];
      // QK^T swapped: S^T[s][q] per m-tile; kf read once serves both m-tiles
      f32x4 sc0[4], sc1[4];
#pragma unroll
      for (int ntt = 0; ntt < 4; ++ntt) {
        sc0[ntt] = f32x4{0.f, 0.f, 0.f, 0.f};
        sc1[ntt] = f32x4{0.f, 0.f, 0.f, 0.f};
      }
      __builtin_amdgcn_s_setprio(1);
#pragma unroll
      for (int kk = 0; kk < 8; ++kk) {
        int byte0 = kk * 64 + lg * 16;
#pragma unroll
        for (int ntt = 0; ntt < 4; ++ntt) {
          int srow = ntt * 16 + l15;
          bf16x8 kf = *(const bf16x8*)(Kc + srow * 512 + (byte0 ^ ((srow & 7) << 4)));
          sc0[ntt] = __builtin_amdgcn_mfma_f32_16x16x32_bf16(kf, qf[0][kk], sc0[ntt], 0, 0, 0);
          sc1[ntt] = __builtin_amdgcn_mfma_f32_16x16x32_bf16(kf, qf[1][kk], sc1[ntt], 0, 0, 0);
        }
      }
      __builtin_amdgcn_s_setprio(0);
#pragma unroll
      for (int m = 0; m < 2; ++m) {
        f32x4* sc = m ? sc1 : sc0;
        // causal mask: lane holds s = kt*64 + ntt*16 + lg*4 + v, q = col l15
        if (kt == ktd) {
          int q_g = qtile * 128 + w * 32 + m * 16 + l15;
#pragma unroll
          for (int ntt = 0; ntt < 4; ++ntt)
#pragma unroll
            for (int v = 0; v < 4; ++v) {
              int s_g = kt * 64 + ntt * 16 + lg * 4 + v;
              if (s_g > q_g) sc[ntt][v] = -1e30f;
            }
        }
        // in-lane max over 16 s-values, then reduce across lg groups
        float pm = fmaxf(fmaxf(sc[0][0], sc[0][1]), fmaxf(sc[0][2], sc[0][3]));
#pragma unroll
        for (int ntt = 1; ntt < 4; ++ntt)
          pm = fmaxf(pm, fmaxf(fmaxf(sc[ntt][0], sc[ntt][1]), fmaxf(sc[ntt][2], sc[ntt][3])));
        pm = fmaxf(pm, __shfl_xor(pm, 16));
        pm = fmaxf(pm, __shfl_xor(pm, 32));
        // defer-max rescale (rare)
        if (__any(pm > m_r[m] + 8.f)) {
          float mnew = fmaxf(m_r[m], pm);
          float rsc = __expf(m_r[m] - mnew);
          m_r[m] = mnew;
          l_r[m] *= rsc;
          float rv[4];
#pragma unroll
          for (int v = 0; v < 4; ++v) rv[v] = __shfl(rsc, lg * 4 + v);
#pragma unroll
          for (int ht = 0; ht < 16; ++ht)
#pragma unroll
            for (int v = 0; v < 4; ++v) accO[m][ht][v] *= rv[v];
        }
        // exp + in-lane sum + 2-shfl reduce
        float rs = 0.f;
#pragma unroll
        for (int ntt = 0; ntt < 4; ++ntt)
#pragma unroll
          for (int v = 0; v < 4; ++v) {
            float p = __expf(sc[ntt][v] - m_r[m]);
            sc[ntt][v] = p;
            rs += p;
          }
        rs += __shfl_xor(rs, 16);
        rs += __shfl_xor(rs, 32);
        l_r[m] += rs;
        // P[q][s] write: 4 consecutive s per (ntt) -> b64 stores, swizzled rows
        char* Pm = (char*)Pl[w][m];
        int pswz = (l15 & 7) << 4;
#pragma unroll
        for (int ntt = 0; ntt < 4; ++ntt) {
          bf16x4v pk = {(bf16_t)sc[ntt][0], (bf16_t)sc[ntt][1], (bf16_t)sc[ntt][2],
                        (bf16_t)sc[ntt][3]};
          *(bf16x4v*)(Pm + l15 * 128 + ((ntt * 32 + lg * 8) ^ pswz)) = pk;
        }
      }
      // PV: O[m] += P[m][16x64] * V[64x256]; vf read once serves both m-tiles
      __builtin_amdgcn_s_setprio(1);
#pragma unroll
      for (int ks = 0; ks < 2; ++ks) {
        int pb = ks * 64 + lg * 16;
        bf16x8 pf0 = *(const bf16x8*)((char*)Pl[w][0] + l15 * 128 + (pb ^ ((l15 & 7) << 4)));
        bf16x8 pf1 = *(const bf16x8*)((char*)Pl[w][1] + l15 * 128 + (pb ^ ((l15 & 7) << 4)));
#pragma unroll
        for (int ht = 0; ht < 16; ++ht) {
          int vrow = ht * 16 + l15;
          bf16x8 vf = *(const bf16x8*)(Vc + vrow * 128 + (pb ^ ((vrow & 7) << 4)));
          accO[0][ht] = __builtin_amdgcn_mfma_f32_16x16x32_bf16(pf0, vf, accO[0][ht], 0, 0, 0);
          accO[1][ht] = __builtin_amdgcn_mfma_f32_16x16x32_bf16(pf1, vf, accO[1][ht], 0, 0, 0);
        }
      }
      __builtin_amdgcn_s_setprio(0);
    }
    __syncthreads();  // implicit vmcnt(0): next tile staged; buf[cur] reusable
    cur ^= 1;
  }
  // epilogue: redistribute l to accO rows, normalize, store
#pragma unroll
  for (int m = 0; m < 2; ++m) {
    float lv[4];
#pragma unroll
    for (int v = 0; v < 4; ++v) lv[v] = __shfl(l_r[m], lg * 4 + v);
#pragma unroll
    for (int ht = 0; ht < 16; ++ht)
#pragma unroll
      for (int v = 0; v < 4; ++v) {
        enc[((size_t)(b * SS + qtile * 128 + w * 32 + m * 16 + lg * 4 + v)) * 2048 + n * 256 +
            ht * 16 + l15] = (bf16_t)(accO[m][ht][v] / lv[v]);
      }
  }
}

extern "C" void kernel_launch(void* const* d_in, const int* in_sizes, int n_in,
                              void* d_out, int out_size, void* d_ws, size_t ws_size,
                              hipStream_t stream) {
  const float* x = (const float*)d_in[0];
  const int* positions = (const int*)d_in[1];
  // d_in[2] = attn_mask (causal tril) — implemented analytically
  const float* qw = (const float*)d_in[3];
  const float* kvw = (const float*)d_in[4];
  const float* outw = (const float*)d_in[5];

  char* ws = (char*)d_ws;
  if (ws_size < (size_t)75497472) return;  // need ~72MB scratch
  bf16_t* xb      = (bf16_t*)(ws);             // [4096][2048]
  bf16_t* qkvwbt  = (bf16_t*)(ws + 16777216);  // [2560][2048]: q rows 0..2047, k 2048..2303, v 2304..2559
  bf16_t* outwbt  = (bf16_t*)(ws + 27262976);  // [2048][2048]
  bf16_t* qkvb    = (bf16_t*)(ws + 35651584);  // [4096][2560]
  bf16_t* vtg     = (bf16_t*)(ws + 56623104);  // [2][256][2048]
  bf16_t* encb    = (bf16_t*)(ws + 58720256);  // [4096][2048]

  cvt_x_kernel<<<8192, 256, 0, stream>>>(x, xb);
  transpose_cvt<<<dim3(8, 64, 8), 256, 0, stream>>>(qw, qkvwbt, 2048, 256);
  transpose_cvt<<<dim3(8, 64, 2), 256, 0, stream>>>(kvw, qkvwbt + (size_t)2048 * 2048, 2048, 256);
  transpose_cvt<<<dim3(64, 64, 1), 256, 0, stream>>>(outw, outwbt, 2048, 2048);
  gemm_bt<0><<<640, 256, 0, stream>>>(xb, qkvwbt, qkvb, 4096, 2560, 2048);
  rope_kernel<<<18432, 256, 0, stream>>>(qkvb, positions);
  vt_kernel<<<dim3(64, 8, 2), 256, 0, stream>>>(qkvb, vtg);
  flash_kernel<<<256, 256, 0, stream>>>(qkvb, vtg, encb);
  gemm_bt<1><<<512, 256, 0, stream>>>(encb, outwbt, d_out, 4096, 2048, 2048);
}

// Round 5
// 260.030 us; speedup vs baseline: 1.0993x; 1.0308x over previous
//
#include <hip/hip_runtime.h>
#include <hip/hip_bf16.h>
#include <stdint.h>

// Problem constants: B=2, S=T=2048, D=2048, N=8 heads, K=1 kv head, H=256
#define BB 2
#define SS 2048
#define DD 2048
#define NHEAD 8
#define HH 256

typedef __bf16 bf16_t;
typedef __bf16 bf16x8 __attribute__((ext_vector_type(8)));
typedef __bf16 bf16x4v __attribute__((ext_vector_type(4)));
typedef float f32x4 __attribute__((ext_vector_type(4)));

__device__ static inline void gload_lds16(const void* g, void* l) {
  __builtin_amdgcn_global_load_lds(
      (__attribute__((address_space(1))) void*)(g),
      (__attribute__((address_space(3))) void*)(l), 16, 0, 0);
}

// ---------------- x -> bf16 ----------------
__global__ void cvt_x_kernel(const float* __restrict__ x, bf16_t* __restrict__ xb) {
  size_t i = ((size_t)blockIdx.x * 256 + threadIdx.x) * 4;
  float4 v = *(const float4*)(x + i);
  bf16x4v o = {(bf16_t)v.x, (bf16_t)v.y, (bf16_t)v.z, (bf16_t)v.w};
  *(bf16x4v*)(xb + i) = o;
}

// ---------------- tiled transpose+convert: out[c][r] = (bf16)in[r][c] ----------------
__global__ void transpose_cvt(const float* __restrict__ in, bf16_t* __restrict__ out,
                              int R, int C) {
  __shared__ float tile[32][33];
  int bx = blockIdx.x, by = blockIdx.y, z = blockIdx.z;
  in  += (size_t)z * R * C;
  out += (size_t)z * R * C;
  int tx = threadIdx.x & 31, ty = threadIdx.x >> 5;  // 32x8
#pragma unroll
  for (int k = 0; k < 4; ++k) {
    int r = by * 32 + ty + k * 8, c = bx * 32 + tx;
    tile[ty + k * 8][tx] = in[(size_t)r * C + c];
  }
  __syncthreads();
#pragma unroll
  for (int k = 0; k < 4; ++k) {
    int c = bx * 32 + ty + k * 8, r = by * 32 + tx;
    out[(size_t)c * R + r] = (bf16_t)tile[tx][ty + k * 8];
  }
}

// ---------------- GEMM: C[M][Nc] = A[M][Kd] * BT[Nc][Kd]^T  (bf16 in, fp32 acc) ----------------
template <int OUT_F32>
__global__ __launch_bounds__(256) void gemm_bt(const bf16_t* __restrict__ A,
                                               const bf16_t* __restrict__ BT,
                                               void* __restrict__ C,
                                               int M, int Nc, int Kd) {
  __shared__ bf16_t At[128 * 64];
  __shared__ bf16_t Bt[128 * 64];
  const int ntiles = Nc >> 7;
  int bid = blockIdx.x;
  int mt = bid / ntiles, ntb = bid % ntiles;
  int t = threadIdx.x;
  int lane = t & 63, w = t >> 6;
  int wm = w >> 1, wn = w & 1;
  int l15 = lane & 15, lg = lane >> 4;
  f32x4 acc[4][4] = {};
  for (int kt = 0; kt < Kd; kt += 64) {
#pragma unroll
    for (int r = 0; r < 4; ++r) {
      int o = t * 16 + r * 4096;     // byte offset into 16KB tile
      int row = o >> 7;              // 128B per row (64 bf16)
      int cb = o & 127;
      gload_lds16(A + (size_t)(mt * 128 + row) * Kd + kt + (cb >> 1), (char*)At + o);
      gload_lds16(BT + (size_t)(ntb * 128 + row) * Kd + kt + (cb >> 1), (char*)Bt + o);
    }
    __syncthreads();
#pragma unroll
    for (int ks = 0; ks < 2; ++ks) {
      bf16x8 af[4], bfr[4];
#pragma unroll
      for (int i = 0; i < 4; ++i) {
        af[i]  = *(const bf16x8*)(At + (wm * 64 + i * 16 + l15) * 64 + ks * 32 + lg * 8);
        bfr[i] = *(const bf16x8*)(Bt + (wn * 64 + i * 16 + l15) * 64 + ks * 32 + lg * 8);
      }
      __builtin_amdgcn_s_setprio(1);
#pragma unroll
      for (int i = 0; i < 4; ++i)
#pragma unroll
        for (int j = 0; j < 4; ++j)
          acc[i][j] = __builtin_amdgcn_mfma_f32_16x16x32_bf16(af[i], bfr[j], acc[i][j], 0, 0, 0);
      __builtin_amdgcn_s_setprio(0);
    }
    __syncthreads();
  }
#pragma unroll
  for (int i = 0; i < 4; ++i)
#pragma unroll
    for (int j = 0; j < 4; ++j) {
      int row = mt * 128 + wm * 64 + i * 16 + lg * 4;
      int col = ntb * 128 + wn * 64 + j * 16 + l15;
#pragma unroll
      for (int v = 0; v < 4; ++v) {
        if (OUT_F32)
          ((float*)C)[(size_t)(row + v) * Nc + col] = acc[i][j][v];
        else
          ((bf16_t*)C)[(size_t)(row + v) * Nc + col] = (bf16_t)acc[i][j][v];
      }
    }
}

// ---------------- RoPE (in-place) on fused qkv [4096][2560] ----------------
__global__ void rope_kernel(bf16_t* __restrict__ qkv, const int* __restrict__ positions) {
  int idx = blockIdx.x * 256 + threadIdx.x;
  const int QP = 4096 * 8 * 128;
  int i, row;
  bf16_t *p1, *p2;
  float scl;
  if (idx < QP) {
    i = idx & 127;
    int nh = (idx >> 7) & 7;
    row = idx >> 10;
    p1 = qkv + (size_t)row * 2560 + nh * 256 + i;
    p2 = p1 + 128;
    scl = 0.0625f;  // H^-0.5 = 1/16
  } else {
    int kk = idx - QP;
    if (kk >= 4096 * 128) return;
    i = kk & 127;
    row = kk >> 7;
    p1 = qkv + (size_t)row * 2560 + 2048 + i;
    p2 = p1 + 128;
    scl = 1.0f;
  }
  float pos = (float)positions[row];
  float ang = pos * __expf(-(float)i * (9.2103403719761836f / 128.f));
  float s = sinf(ang), c = cosf(ang);
  float x1 = (float)*p1, x2 = (float)*p2;
  *p1 = (bf16_t)((x1 * c - x2 * s) * scl);
  *p2 = (bf16_t)((x2 * c + x1 * s) * scl);
}

// ---------------- V transpose (LDS-tiled): vt[b][h][s] = qkv[(b*S+s)][2304+h] ----------------
__global__ void vt_kernel(const bf16_t* __restrict__ qkv, bf16_t* __restrict__ vt) {
  __shared__ bf16_t tile[32][34];
  int bx = blockIdx.x;  // s-tile (64)
  int by = blockIdx.y;  // h-tile (8)
  int b = blockIdx.z;
  int tx = threadIdx.x & 31, ty = threadIdx.x >> 5;
#pragma unroll
  for (int k = 0; k < 4; ++k) {
    int s = bx * 32 + ty + k * 8, h = by * 32 + tx;
    tile[ty + k * 8][tx] = qkv[((size_t)(b * SS + s)) * 2560 + 2304 + h];
  }
  __syncthreads();
#pragma unroll
  for (int k = 0; k < 4; ++k) {
    int h = by * 32 + ty + k * 8, s = bx * 32 + tx;
    vt[((size_t)(b * HH + h)) * 2048 + s] = tile[tx][ty + k * 8];
  }
}

// ---------------- Flash attention (8 waves, s-split, fat waves, swapped QK^T) ----------------
// grid 256, block 512 = 8 waves. Wave w: q-rows (w&3)*32 (M_rep=2), s-half (w>>2)
// of each 64-wide KV tile. Independent online-softmax partials per wave; pairs
// (w, w^4) merged at end of each q-tile via LDS (stats + scaled-O exchange).
// 2 waves/SIMD -> cross-wave latency hiding. Block does q-tiles pr and 15-pr.
__global__ __launch_bounds__(512, 2) void flash_kernel(const bf16_t* __restrict__ qkv,
                                                       const bf16_t* __restrict__ vtg,
                                                       bf16_t* __restrict__ enc) {
  __shared__ __attribute__((aligned(16))) char LDSRAW[147456];
  // [0,64K): K dbuf [2][64][256] bf16 (512B rows, XOR-swizzled)
  // [64K,128K): V^T dbuf [2][256][64] bf16 (128B rows, XOR-swizzled)
  // [128K,144K): per-wave P [16 q][2 m][32 s] bf16 (128B rows, XOR-swizzled)
  // overlays (disjoint in time): stats @128K (2KB); Oex @0 [4 pair][32 q][256 h] f32
  int bid = blockIdx.x;
  int b = bid >> 7, n = (bid >> 4) & 7, pr = bid & 15;
  int t = threadIdx.x, lane = t & 63, w = t >> 6;
  int l15 = lane & 15, lg = lane >> 4;
  int wq = w & 3, sh = w >> 2;
  char* Kt0 = LDSRAW;
  char* Vt0 = LDSRAW + 65536;
  char* Pw  = LDSRAW + 131072 + w * 2048;
  float* stw = (float*)(LDSRAW + 131072);
  // staging source precompute (pre-swizzled global addresses, LDS dest linear)
  int rk0 = t >> 5;  // K row base (0..15), +16 per r
  int cbk = ((t * 16) & 511) ^ ((rk0 & 7) << 4);
  const bf16_t* kptr = qkv + ((size_t)(b * SS + rk0)) * 2560 + 2048 + (cbk >> 1);
  int rv0 = t >> 3;  // V row base (0..63), +64 per r
  int cbv = ((t & 7) * 16) ^ ((rv0 & 7) << 4);
  const bf16_t* vptr = vtg + ((size_t)(b * HH + rv0)) * 2048 + (cbv >> 1);

  for (int half = 0; half < 2; ++half) {
    int qtile = half ? (15 - pr) : pr;
    int qmin = qtile * 128 + wq * 32;
    int ktlast = 2 * qtile + 1;
    // Q fragments: rows qmin + m*16 + l15
    bf16x8 qf[2][8];
#pragma unroll
    for (int m = 0; m < 2; ++m) {
      const bf16_t* qrow = qkv + ((size_t)(b * SS + qmin + m * 16 + l15)) * 2560 + n * 256;
#pragma unroll
      for (int kk = 0; kk < 8; ++kk) qf[m][kk] = *(const bf16x8*)(qrow + kk * 32 + lg * 8);
    }
    f32x4 accO[2][16];
#pragma unroll
    for (int m = 0; m < 2; ++m)
#pragma unroll
      for (int ht = 0; ht < 16; ++ht) accO[m][ht] = f32x4{0.f, 0.f, 0.f, 0.f};
    float m_r[2] = {-1e30f, -1e30f}, l_r[2] = {0.f, 0.f};
    // prologue: stage tile 0 into buf 0
#pragma unroll
    for (int r = 0; r < 4; ++r) {
      gload_lds16(kptr + (size_t)r * 16 * 2560, Kt0 + t * 16 + r * 8192);
      gload_lds16(vptr + (size_t)r * 64 * 2048, Vt0 + t * 16 + r * 8192);
    }
    __syncthreads();
    int cur = 0;
    for (int kt = 0; kt <= ktlast; ++kt) {
      // issue next tile's staging FIRST (hidden under compute below)
      if (kt < ktlast) {
        int nxt = cur ^ 1;
        const bf16_t* ks = kptr + (size_t)(kt + 1) * 64 * 2560;
        const bf16_t* vs = vptr + (size_t)(kt + 1) * 64;
#pragma unroll
        for (int r = 0; r < 4; ++r) {
          gload_lds16(ks + (size_t)r * 16 * 2560, Kt0 + nxt * 32768 + t * 16 + r * 8192);
          gload_lds16(vs + (size_t)r * 64 * 2048, Vt0 + nxt * 32768 + t * 16 + r * 8192);
        }
      }
      int smin = kt * 64 + sh * 32;
      if (smin <= qmin + 31) {  // wave active for this sub-tile
        const char* Kc = Kt0 + cur * 32768;
        const char* Vc = Vt0 + cur * 32768;
        // QK^T swapped: S^T[s 32][q 16] per m; kf read once serves both m
        f32x4 sc[2][2];
#pragma unroll
        for (int m = 0; m < 2; ++m)
#pragma unroll
          for (int ntt = 0; ntt < 2; ++ntt) sc[m][ntt] = f32x4{0.f, 0.f, 0.f, 0.f};
        __builtin_amdgcn_s_setprio(1);
#pragma unroll
        for (int kk = 0; kk < 8; ++kk) {
          int byte0 = kk * 64 + lg * 16;
#pragma unroll
          for (int ntt = 0; ntt < 2; ++ntt) {
            int srow = sh * 32 + ntt * 16 + l15;
            bf16x8 kf = *(const bf16x8*)(Kc + srow * 512 + (byte0 ^ ((srow & 7) << 4)));
            sc[0][ntt] = __builtin_amdgcn_mfma_f32_16x16x32_bf16(kf, qf[0][kk], sc[0][ntt], 0, 0, 0);
            sc[1][ntt] = __builtin_amdgcn_mfma_f32_16x16x32_bf16(kf, qf[1][kk], sc[1][ntt], 0, 0, 0);
          }
        }
        __builtin_amdgcn_s_setprio(0);
        if (smin + 31 > qmin) {  // diagonal-crossing: causal mask
#pragma unroll
          for (int m = 0; m < 2; ++m) {
            int q_g = qmin + m * 16 + l15;
#pragma unroll
            for (int ntt = 0; ntt < 2; ++ntt)
#pragma unroll
              for (int v = 0; v < 4; ++v) {
                int s_g = smin + ntt * 16 + lg * 4 + v;
                if (s_g > q_g) sc[m][ntt][v] = -1e30f;
              }
          }
        }
        // softmax partials (per m): in-lane over 8 + 2 shfls
#pragma unroll
        for (int m = 0; m < 2; ++m) {
          float pm = fmaxf(fmaxf(sc[m][0][0], sc[m][0][1]), fmaxf(sc[m][0][2], sc[m][0][3]));
          pm = fmaxf(pm, fmaxf(fmaxf(sc[m][1][0], sc[m][1][1]), fmaxf(sc[m][1][2], sc[m][1][3])));
          pm = fmaxf(pm, __shfl_xor(pm, 16));
          pm = fmaxf(pm, __shfl_xor(pm, 32));
          if (__any(pm > m_r[m] + 8.f)) {  // defer-max rescale (rare)
            float mnew = fmaxf(m_r[m], pm);
            float rsc = __expf(m_r[m] - mnew);
            m_r[m] = mnew;
            l_r[m] *= rsc;
            float rv[4];
#pragma unroll
            for (int v = 0; v < 4; ++v) rv[v] = __shfl(rsc, lg * 4 + v);
#pragma unroll
            for (int ht = 0; ht < 16; ++ht)
#pragma unroll
              for (int v = 0; v < 4; ++v) accO[m][ht][v] *= rv[v];
          }
          float rs = 0.f;
#pragma unroll
          for (int ntt = 0; ntt < 2; ++ntt)
#pragma unroll
            for (int v = 0; v < 4; ++v) {
              float p = __expf(sc[m][ntt][v] - m_r[m]);
              sc[m][ntt][v] = p;
              rs += p;
            }
          rs += __shfl_xor(rs, 16);
          rs += __shfl_xor(rs, 32);
          l_r[m] += rs;
          // P write: row q=l15 (128B rows: m*64 + s*2), swizzle ^((q&7)<<4)
          int pswz = (l15 & 7) << 4;
#pragma unroll
          for (int ntt = 0; ntt < 2; ++ntt) {
            bf16x4v pk = {(bf16_t)sc[m][ntt][0], (bf16_t)sc[m][ntt][1], (bf16_t)sc[m][ntt][2],
                          (bf16_t)sc[m][ntt][3]};
            *(bf16x4v*)(Pw + l15 * 128 + ((m * 64 + ntt * 32 + lg * 8) ^ pswz)) = pk;
          }
        }
        // PV: O[m] += P[m][16q x 32s] * V[32s x 256h]; vf read once serves both m
        bf16x8 pf0 = *(const bf16x8*)(Pw + l15 * 128 + ((0 + lg * 16) ^ ((l15 & 7) << 4)));
        bf16x8 pf1 = *(const bf16x8*)(Pw + l15 * 128 + ((64 + lg * 16) ^ ((l15 & 7) << 4)));
        __builtin_amdgcn_s_setprio(1);
#pragma unroll
        for (int ht = 0; ht < 16; ++ht) {
          int vrow = ht * 16 + l15;
          bf16x8 vf =
              *(const bf16x8*)(Vc + vrow * 128 + ((sh * 64 + lg * 16) ^ ((vrow & 7) << 4)));
          accO[0][ht] = __builtin_amdgcn_mfma_f32_16x16x32_bf16(pf0, vf, accO[0][ht], 0, 0, 0);
          accO[1][ht] = __builtin_amdgcn_mfma_f32_16x16x32_bf16(pf1, vf, accO[1][ht], 0, 0, 0);
        }
        __builtin_amdgcn_s_setprio(0);
      }
      __syncthreads();  // implicit vmcnt(0): next tile staged; buf[cur] reusable
      cur ^= 1;
    }
    // ---- merge wave pairs (w, w^4): disjoint s-sets, same q rows ----
    if (lg == 0) {
#pragma unroll
      for (int m = 0; m < 2; ++m) {
        stw[((w * 2 + m) * 16 + l15) * 2 + 0] = m_r[m];
        stw[((w * 2 + m) * 16 + l15) * 2 + 1] = l_r[m];
      }
    }
    __syncthreads();
    int peer = w ^ 4;
    float pm2[2], pl2[2];
#pragma unroll
    for (int m = 0; m < 2; ++m) {
      pm2[m] = stw[((peer * 2 + m) * 16 + l15) * 2 + 0];
      pl2[m] = stw[((peer * 2 + m) * 16 + l15) * 2 + 1];
    }
    float* Ox = (float*)LDSRAW + (size_t)wq * 8192;  // [32 q][256 h]
    if (sh == 1) {  // upper: write O2 * exp(m2 - m*)
#pragma unroll
      for (int m = 0; m < 2; ++m) {
        float sc2 = __expf(m_r[m] - fmaxf(m_r[m], pm2[m]));
        float s2v[4];
#pragma unroll
        for (int v = 0; v < 4; ++v) s2v[v] = __shfl(sc2, lg * 4 + v);
#pragma unroll
        for (int ht = 0; ht < 16; ++ht)
#pragma unroll
          for (int v = 0; v < 4; ++v)
            Ox[(m * 16 + lg * 4 + v) * 256 + ht * 16 + l15] = accO[m][ht][v] * s2v[v];
      }
    }
    __syncthreads();
    if (sh == 0) {  // lower: combine, normalize, store
#pragma unroll
      for (int m = 0; m < 2; ++m) {
        float mstar = fmaxf(m_r[m], pm2[m]);
        float sc1 = __expf(m_r[m] - mstar);
        float lstar = l_r[m] * sc1 + pl2[m] * __expf(pm2[m] - mstar);
        float rinv = 1.f / lstar;
        float s1v[4], riv[4];
#pragma unroll
        for (int v = 0; v < 4; ++v) {
          s1v[v] = __shfl(sc1, lg * 4 + v);
          riv[v] = __shfl(rinv, lg * 4 + v);
        }
#pragma unroll
        for (int ht = 0; ht < 16; ++ht)
#pragma unroll
          for (int v = 0; v < 4; ++v) {
            float o = (accO[m][ht][v] * s1v[v] + Ox[(m * 16 + lg * 4 + v) * 256 + ht * 16 + l15]) *
                      riv[v];
            enc[((size_t)(b * SS + qmin + m * 16 + lg * 4 + v)) * 2048 + n * 256 + ht * 16 + l15] =
                (bf16_t)o;
          }
      }
    }
    __syncthreads();  // Oex region reused as K/V staging next half
  }
}

extern "C" void kernel_launch(void* const* d_in, const int* in_sizes, int n_in,
                              void* d_out, int out_size, void* d_ws, size_t ws_size,
                              hipStream_t stream) {
  const float* x = (const float*)d_in[0];
  const int* positions = (const int*)d_in[1];
  // d_in[2] = attn_mask (causal tril) — implemented analytically
  const float* qw = (const float*)d_in[3];
  const float* kvw = (const float*)d_in[4];
  const float* outw = (const float*)d_in[5];

  char* ws = (char*)d_ws;
  if (ws_size < (size_t)75497472) return;  // need ~72MB scratch
  bf16_t* xb      = (bf16_t*)(ws);             // [4096][2048]
  bf16_t* qkvwbt  = (bf16_t*)(ws + 16777216);  // [2560][2048]: q rows 0..2047, k 2048..2303, v 2304..2559
  bf16_t* outwbt  = (bf16_t*)(ws + 27262976);  // [2048][2048]
  bf16_t* qkvb    = (bf16_t*)(ws + 35651584);  // [4096][2560]
  bf16_t* vtg     = (bf16_t*)(ws + 56623104);  // [2][256][2048]
  bf16_t* encb    = (bf16_t*)(ws + 58720256);  // [4096][2048]

  cvt_x_kernel<<<8192, 256, 0, stream>>>(x, xb);
  transpose_cvt<<<dim3(8, 64, 8), 256, 0, stream>>>(qw, qkvwbt, 2048, 256);
  transpose_cvt<<<dim3(8, 64, 2), 256, 0, stream>>>(kvw, qkvwbt + (size_t)2048 * 2048, 2048, 256);
  transpose_cvt<<<dim3(64, 64, 1), 256, 0, stream>>>(outw, outwbt, 2048, 2048);
  gemm_bt<0><<<640, 256, 0, stream>>>(xb, qkvwbt, qkvb, 4096, 2560, 2048);
  rope_kernel<<<18432, 256, 0, stream>>>(qkvb, positions);
  vt_kernel<<<dim3(64, 8, 2), 256, 0, stream>>>(qkvb, vtg);
  flash_kernel<<<256, 512, 0, stream>>>(qkvb, vtg, encb);
  gemm_bt<1><<<512, 256, 0, stream>>>(encb, outwbt, d_out, 4096, 2048, 2048);
}